// Round 3
// baseline (37.275 us; speedup 1.0000x reference)
//
#include <hip/hip_runtime.h>

// Problem constants (match setup_inputs)
#define BB   2
#define CC   3
#define HH   192
#define WW   192
#define LL   19
#define PADR 9
#define HP   (HH + 2 * PADR)   // 210
#define WP   (WW + 2 * PADR)   // 210
#define HWN  (HH * WW)         // 36864
#define TAPS (LL * LL)         // 361

#define PIXB  8                 // pixels per block (one per wave)
#define TROWS LL                // 19
#define TCOLS (PIXB + LL - 1)   // 26
#define TF4   (TROWS * TCOLS)   // 494 float4 slots used
#define NCHNK (HWN / PIXB)      // 4608 chunks per kb

#define GLOAD_LDS16(g, l)                                                     \
    __builtin_amdgcn_global_load_lds(                                         \
        (const __attribute__((address_space(1))) void*)(g),                   \
        (__attribute__((address_space(3))) void*)(l), 16, 0, 0)

// Reflect-pad + rearrange image into (kb, HP, WP, float4) where component j
// holds channel-slot n = kb + BB*j (n = b*CC + c ordering of the reference).
__global__ __launch_bounds__(256) void pad_rearrange(
    const float* __restrict__ x, float4* __restrict__ img) {
    int idx = blockIdx.x * blockDim.x + threadIdx.x;
    const int total = BB * HP * WP;
    if (idx >= total) return;
    int xw  = idx % WP;
    int tmp = idx / WP;
    int y   = tmp % HP;
    int kb  = tmp / HP;
    int oy = y - PADR;
    oy = oy < 0 ? -oy : (oy >= HH ? 2 * HH - 2 - oy : oy);
    int ox = xw - PADR;
    ox = ox < 0 ? -ox : (ox >= WW ? 2 * WW - 2 - ox : ox);
    float v[3];
#pragma unroll
    for (int j = 0; j < 3; ++j) {
        int n = kb + BB * j;  // n = b*CC + c, with n % BB == kb
        v[j] = x[((size_t)n * HH + oy) * WW + ox];
    }
    img[idx] = make_float4(v[0], v[1], v[2], 0.0f);
}

// 512-thread block = 8 waves = 8 consecutive pixels of one row (one kb).
// Stage the shared 19x26 float4 image tile into LDS (1 global_load_lds per
// thread, linear dest + per-lane source), then each wave runs the round-0
// pattern: 6 coalesced kernel dword loads + 6 ds_read_b128 image reads +
// butterfly reduce; lane 0 stores 3 channels.
__global__ __launch_bounds__(512, 8) void sv_blur_tile(
    const float* __restrict__ kern, const float4* __restrict__ img,
    float* __restrict__ out) {
    __shared__ float4 tile[512];   // 8 KB (slots 494..511 written, never read)

    int bx    = blockIdx.x;
    int kb    = bx / NCHNK;
    int chunk = bx % NCHNK;
    int p0    = chunk * PIXB;
    int h     = p0 / WW, w0 = p0 % WW;   // w0 multiple of 8; no row crossing
    int tid   = threadIdx.x;
    int wv    = tid >> 6, lane = tid & 63;

    // ---- stage image tile: rows h..h+18, cols w0..w0+25 of padded image ----
    {
        int li = tid;                       // dest slot (linear)
        int si = li < TF4 ? li : TF4 - 1;   // clamp source for tail slots
        int r  = si / TCOLS, c = si % TCOLS;
        const float4* srow = img + ((size_t)kb * HP + h) * WP + w0;
        GLOAD_LDS16(srow + (size_t)r * WP + c,
                    (char*)tile + (size_t)(wv << 6) * sizeof(float4));
    }
    __syncthreads();

    // ---- compute: wave wv handles pixel p0+wv ----
    int p = p0 + wv;
    const float* kbase = kern + (size_t)(kb * HWN + p) * TAPS;
    float a0 = 0.f, a1 = 0.f, a2 = 0.f;
#pragma unroll
    for (int it = 0; it < 6; ++it) {
        int t = lane + (it << 6);
        if (t < TAPS) {
            float  kv = kbase[t];
            int    ki = t / LL, kj = t % LL;
            float4 iv = tile[ki * TCOLS + wv + kj];
            a0 = fmaf(kv, iv.x, a0);
            a1 = fmaf(kv, iv.y, a1);
            a2 = fmaf(kv, iv.z, a2);
        }
    }
#pragma unroll
    for (int m = 32; m; m >>= 1) {
        a0 += __shfl_xor(a0, m, 64);
        a1 += __shfl_xor(a1, m, 64);
        a2 += __shfl_xor(a2, m, 64);
    }
    if (lane == 0) {
        out[(size_t)(kb + 0 * BB) * HWN + p] = a0;
        out[(size_t)(kb + 1 * BB) * HWN + p] = a1;
        out[(size_t)(kb + 2 * BB) * HWN + p] = a2;
    }
}

// Fallback (no workspace): inline reflect, 3 scalar image loads per tap.
__global__ __launch_bounds__(256) void sv_blur_nows(
    const float* __restrict__ kern, const float* __restrict__ x,
    float* __restrict__ out) {
    int wid  = (blockIdx.x * blockDim.x + threadIdx.x) >> 6;
    int lane = threadIdx.x & 63;
    int p  = wid % HWN;
    int kb = wid / HWN;
    int h = p / WW, w = p % WW;
    const float* kbase = kern + (size_t)(kb * HWN + p) * TAPS;
    float a[3] = {0.f, 0.f, 0.f};
#pragma unroll
    for (int it = 0; it < 6; ++it) {
        int t = lane + 64 * it;
        if (t < TAPS) {
            float kv = kbase[t];
            int ki = t / LL, kj = t % LL;
            int oy = h + ki - PADR;
            oy = oy < 0 ? -oy : (oy >= HH ? 2 * HH - 2 - oy : oy);
            int ox = w + kj - PADR;
            ox = ox < 0 ? -ox : (ox >= WW ? 2 * WW - 2 - ox : ox);
#pragma unroll
            for (int j = 0; j < 3; ++j) {
                int n = kb + BB * j;
                a[j] = fmaf(kv, x[((size_t)n * HH + oy) * WW + ox], a[j]);
            }
        }
    }
#pragma unroll
    for (int m = 32; m; m >>= 1) {
        a[0] += __shfl_xor(a[0], m, 64);
        a[1] += __shfl_xor(a[1], m, 64);
        a[2] += __shfl_xor(a[2], m, 64);
    }
    if (lane == 0) {
#pragma unroll
        for (int j = 0; j < 3; ++j)
            out[(size_t)(kb + j * BB) * HWN + p] = a[j];
    }
}

extern "C" void kernel_launch(void* const* d_in, const int* in_sizes, int n_in,
                              void* d_out, int out_size, void* d_ws, size_t ws_size,
                              hipStream_t stream) {
    const float* x    = (const float*)d_in[0];
    const float* kern = (const float*)d_in[1];
    float*       out  = (float*)d_out;

    const size_t need = (size_t)BB * HP * WP * sizeof(float4);  // ~1.41 MB

    if (ws_size >= need) {
        float4* img = (float4*)d_ws;
        const int ptotal = BB * HP * WP;
        pad_rearrange<<<(ptotal + 255) / 256, 256, 0, stream>>>(x, img);
        sv_blur_tile<<<BB * NCHNK, 512, 0, stream>>>(kern, img, out);
    } else {
        const int nwaves  = BB * HWN;
        const int nblocks = nwaves / 4;
        sv_blur_nows<<<nblocks, 256, 0, stream>>>(kern, x, out);
    }
}

// Round 4
// 35.491 us; speedup vs baseline: 1.0503x; 1.0503x over previous
//
#include <hip/hip_runtime.h>

// Problem constants (match setup_inputs)
#define BB   2
#define CC   3
#define HH   192
#define WW   192
#define LL   19
#define PADR 9
#define HP   (HH + 2 * PADR)   // 210
#define WP   (WW + 2 * PADR)   // 210
#define HWN  (HH * WW)         // 36864
#define TAPS (LL * LL)         // 361

#define PIXPW 8                 // consecutive same-row pixels per wave
#define NGRP  (HWN / PIXPW)     // 4608 pixel-groups per kb

// Reflect-pad + rearrange image into (kb, HP, WP, float4) where component j
// holds channel-slot n = kb + BB*j (n = b*CC + c ordering of the reference).
__global__ __launch_bounds__(256) void pad_rearrange(
    const float* __restrict__ x, float4* __restrict__ img) {
    int idx = blockIdx.x * blockDim.x + threadIdx.x;
    const int total = BB * HP * WP;
    if (idx >= total) return;
    int xw  = idx % WP;
    int tmp = idx / WP;
    int y   = tmp % HP;
    int kb  = tmp / HP;
    int oy = y - PADR;
    oy = oy < 0 ? -oy : (oy >= HH ? 2 * HH - 2 - oy : oy);
    int ox = xw - PADR;
    ox = ox < 0 ? -ox : (ox >= WW ? 2 * WW - 2 - ox : ox);
    float v[3];
#pragma unroll
    for (int j = 0; j < 3; ++j) {
        int n = kb + BB * j;  // n = b*CC + c, with n % BB == kb
        v[j] = x[((size_t)n * HH + oy) * WW + ox];
    }
    img[idx] = make_float4(v[0], v[1], v[2], 0.0f);
}

// One wave per 8 consecutive same-row pixels of one kb. Per-lane tap metadata
// (tap index t, image float4 offset, validity) computed ONCE per wave and
// reused across pixels. Pixels processed 2 at a time (two accumulator sets)
// so one pixel's shfl-reduce chain overlaps the sibling's loads/FMAs.
__global__ __launch_bounds__(256) void sv_blur8(
    const float* __restrict__ kern, const float4* __restrict__ img,
    float* __restrict__ out) {
    int wid  = (blockIdx.x * blockDim.x + threadIdx.x) >> 6;
    int lane = threadIdx.x & 63;
    int kb   = wid / NGRP;
    int grp  = wid % NGRP;
    int p0   = grp * PIXPW;
    int h    = p0 / WW, w0 = p0 % WW;   // w0 multiple of 8: no row crossing

    // per-lane tap metadata, computed once
    int t_[6], ioff_[6];
    bool v_[6];
#pragma unroll
    for (int it = 0; it < 6; ++it) {
        int t = lane + (it << 6);
        t_[it]    = t;
        v_[it]    = t < TAPS;
        int tt    = t < TAPS ? t : 0;
        int ki    = tt / LL, kj = tt % LL;
        ioff_[it] = ki * WP + kj;       // float4 offset into padded image
    }

    const float*  kb0 = kern + (size_t)(kb * HWN + p0) * TAPS;
    const float4* ib0 = img + ((size_t)kb * HP + h) * WP + w0;

#pragma unroll
    for (int pp = 0; pp < PIXPW / 2; ++pp) {
        int pxA = 2 * pp, pxB = 2 * pp + 1;
        const float*  kA = kb0 + (size_t)pxA * TAPS;
        const float*  kB = kb0 + (size_t)pxB * TAPS;
        const float4* iA = ib0 + pxA;
        const float4* iB = ib0 + pxB;
        float a0 = 0.f, a1 = 0.f, a2 = 0.f;
        float b0 = 0.f, b1 = 0.f, b2 = 0.f;
#pragma unroll
        for (int it = 0; it < 6; ++it) {
            if (v_[it]) {
                float  kvA = kA[t_[it]];
                float  kvB = kB[t_[it]];
                float4 ivA = iA[ioff_[it]];
                float4 ivB = iB[ioff_[it]];
                a0 = fmaf(kvA, ivA.x, a0);
                a1 = fmaf(kvA, ivA.y, a1);
                a2 = fmaf(kvA, ivA.z, a2);
                b0 = fmaf(kvB, ivB.x, b0);
                b1 = fmaf(kvB, ivB.y, b1);
                b2 = fmaf(kvB, ivB.z, b2);
            }
        }
#pragma unroll
        for (int m = 32; m; m >>= 1) {
            a0 += __shfl_xor(a0, m, 64);
            a1 += __shfl_xor(a1, m, 64);
            a2 += __shfl_xor(a2, m, 64);
            b0 += __shfl_xor(b0, m, 64);
            b1 += __shfl_xor(b1, m, 64);
            b2 += __shfl_xor(b2, m, 64);
        }
        if (lane == 0) {
            int pA = p0 + pxA, pB = p0 + pxB;
            out[(size_t)(kb + 0 * BB) * HWN + pA] = a0;
            out[(size_t)(kb + 1 * BB) * HWN + pA] = a1;
            out[(size_t)(kb + 2 * BB) * HWN + pA] = a2;
            out[(size_t)(kb + 0 * BB) * HWN + pB] = b0;
            out[(size_t)(kb + 1 * BB) * HWN + pB] = b1;
            out[(size_t)(kb + 2 * BB) * HWN + pB] = b2;
        }
    }
}

// Fallback (no workspace): inline reflect, 3 scalar image loads per tap.
__global__ __launch_bounds__(256) void sv_blur_nows(
    const float* __restrict__ kern, const float* __restrict__ x,
    float* __restrict__ out) {
    int wid  = (blockIdx.x * blockDim.x + threadIdx.x) >> 6;
    int lane = threadIdx.x & 63;
    int p  = wid % HWN;
    int kb = wid / HWN;
    int h = p / WW, w = p % WW;
    const float* kbase = kern + (size_t)(kb * HWN + p) * TAPS;
    float a[3] = {0.f, 0.f, 0.f};
#pragma unroll
    for (int it = 0; it < 6; ++it) {
        int t = lane + 64 * it;
        if (t < TAPS) {
            float kv = kbase[t];
            int ki = t / LL, kj = t % LL;
            int oy = h + ki - PADR;
            oy = oy < 0 ? -oy : (oy >= HH ? 2 * HH - 2 - oy : oy);
            int ox = w + kj - PADR;
            ox = ox < 0 ? -ox : (ox >= WW ? 2 * WW - 2 - ox : ox);
#pragma unroll
            for (int j = 0; j < 3; ++j) {
                int n = kb + BB * j;
                a[j] = fmaf(kv, x[((size_t)n * HH + oy) * WW + ox], a[j]);
            }
        }
    }
#pragma unroll
    for (int m = 32; m; m >>= 1) {
        a[0] += __shfl_xor(a[0], m, 64);
        a[1] += __shfl_xor(a[1], m, 64);
        a[2] += __shfl_xor(a[2], m, 64);
    }
    if (lane == 0) {
#pragma unroll
        for (int j = 0; j < 3; ++j)
            out[(size_t)(kb + j * BB) * HWN + p] = a[j];
    }
}

extern "C" void kernel_launch(void* const* d_in, const int* in_sizes, int n_in,
                              void* d_out, int out_size, void* d_ws, size_t ws_size,
                              hipStream_t stream) {
    const float* x    = (const float*)d_in[0];
    const float* kern = (const float*)d_in[1];
    float*       out  = (float*)d_out;

    const size_t need = (size_t)BB * HP * WP * sizeof(float4);  // ~1.41 MB

    if (ws_size >= need) {
        float4* img = (float4*)d_ws;
        const int ptotal = BB * HP * WP;
        pad_rearrange<<<(ptotal + 255) / 256, 256, 0, stream>>>(x, img);
        const int nwaves  = BB * NGRP;          // 9216
        const int nblocks = nwaves / 4;         // 2304 (256 thr = 4 waves)
        sv_blur8<<<nblocks, 256, 0, stream>>>(kern, img, out);
    } else {
        const int nwaves  = BB * HWN;
        const int nblocks = nwaves / 4;
        sv_blur_nows<<<nblocks, 256, 0, stream>>>(kern, x, out);
    }
}